// Round 7
// baseline (211.887 us; speedup 1.0000x reference)
//
#include <hip/hip_runtime.h>

namespace {

constexpr int kH  = 1024;
constexpr int kW  = 1024;
constexpr int kHW = kH * kW;
constexpr int kSH = 68;           // int(1023/16)+1+2*2
constexpr int kSW = 68;
constexpr int kD  = 8;            // max depth; features uniform [0,1) -> depth <= 8
constexpr int kT3 = kSH * kSW * kD * kD * kD;   // 2,367,488 cells per channel

// ---- ws layout ----
// bytes [0..256):    hdrF floats [0..2]=channel mins; ints at +8 words: dr,dg,db
// bytes [1024..7168): minmax partials, 256 blocks x 6 floats
// bytes [8192..):    gridA (splat)

__global__ void minmax_kernel(const float* __restrict__ feat, float* __restrict__ part) {
    float mn[3] = {1e30f, 1e30f, 1e30f};
    float mx[3] = {-1e30f, -1e30f, -1e30f};
    int tid = blockIdx.x * blockDim.x + threadIdx.x;
    int stride = gridDim.x * blockDim.x;
    for (int p = tid; p < kHW; p += stride) {
        #pragma unroll
        for (int c = 0; c < 3; ++c) {
            float v = feat[p * 3 + c];
            mn[c] = fminf(mn[c], v);
            mx[c] = fmaxf(mx[c], v);
        }
    }
    #pragma unroll
    for (int off = 32; off > 0; off >>= 1) {
        #pragma unroll
        for (int c = 0; c < 3; ++c) {
            mn[c] = fminf(mn[c], __shfl_down(mn[c], off, 64));
            mx[c] = fmaxf(mx[c], __shfl_down(mx[c], off, 64));
        }
    }
    __shared__ float smn[4][3], smx[4][3];
    int wave = threadIdx.x >> 6;
    if ((threadIdx.x & 63) == 0) {
        #pragma unroll
        for (int c = 0; c < 3; ++c) { smn[wave][c] = mn[c]; smx[wave][c] = mx[c]; }
    }
    __syncthreads();
    if (threadIdx.x == 0) {
        #pragma unroll
        for (int c = 0; c < 3; ++c) {
            part[blockIdx.x * 6 + c]     = fminf(fminf(smn[0][c], smn[1][c]), fminf(smn[2][c], smn[3][c]));
            part[blockIdx.x * 6 + 3 + c] = fmaxf(fmaxf(smx[0][c], smx[1][c]), fmaxf(smx[2][c], smx[3][c]));
        }
    }
}

__global__ void params_kernel(const float* __restrict__ part, float* __restrict__ hdrF) {
    int t = threadIdx.x;   // 256 threads, one per partial
    float mn[3], mx[3];
    #pragma unroll
    for (int c = 0; c < 3; ++c) { mn[c] = part[t * 6 + c]; mx[c] = part[t * 6 + 3 + c]; }
    #pragma unroll
    for (int off = 32; off > 0; off >>= 1) {
        #pragma unroll
        for (int c = 0; c < 3; ++c) {
            mn[c] = fminf(mn[c], __shfl_down(mn[c], off, 64));
            mx[c] = fmaxf(mx[c], __shfl_down(mx[c], off, 64));
        }
    }
    __shared__ float smn[4][3], smx[4][3];
    int wave = t >> 6;
    if ((t & 63) == 0) {
        #pragma unroll
        for (int c = 0; c < 3; ++c) { smn[wave][c] = mn[c]; smx[wave][c] = mx[c]; }
    }
    __syncthreads();
    if (t == 0) {
        int* ip = (int*)(hdrF + 8);
        #pragma unroll
        for (int c = 0; c < 3; ++c) {
            float bmn = fminf(fminf(smn[0][c], smn[1][c]), fminf(smn[2][c], smn[3][c]));
            float bmx = fmaxf(fmaxf(smx[0][c], smx[1][c]), fmaxf(smx[2][c], smx[3][c]));
            float delta = bmx - bmn;                        // fp32 sub, like numpy
            int depth = (int)((double)delta / 0.25) + 1 + 4;
            if (depth > kD) depth = kD;
            if (depth < 1) depth = 1;
            hdrF[c] = bmn;
            ip[c] = depth;
        }
    }
}

// Privatized splat: one block per INTERIOR cell [2,66]^2 (boundary cells are
// never read — consumers treat out-of-range cells as zero). LDS histogram,
// coalesced stores, zero global atomics.
__global__ void splat_kernel(const float* __restrict__ feat,
                             const float* __restrict__ inp,
                             const float* __restrict__ hdrF,
                             float* __restrict__ grid) {
    int ix = blockIdx.x, iy = blockIdx.y;          // band index 0..64
    int y0 = (iy == 0) ? 0 : 16 * iy - 8;
    int x0 = (ix == 0) ? 0 : 16 * ix - 8;
    int h = (iy == 0 || iy == 64) ? 8 : 16;
    int w = (ix == 0 || ix == 64) ? 8 : 16;

    __shared__ float acc[3 * 512];
    for (int i = threadIdx.x; i < 3 * 512; i += 256) acc[i] = 0.0f;
    __syncthreads();

    int t = threadIdx.x;
    int n = w * h;
    if (t < n) {
        int lx = t & (w - 1);
        int ly = (w == 16) ? (t >> 4) : (t >> 3);
        int y = y0 + ly, x = x0 + lx;
        int p = (y << 10) + x;
        float v0 = feat[p * 3 + 0] - hdrF[0];
        float v1 = feat[p * 3 + 1] - hdrF[1];
        float v2 = feat[p * 3 + 2] - hdrF[2];
        int sr = (int)(v0 * 4.0f + 0.5f) + 2;   // /0.25 == *4 exact
        int sg = (int)(v1 * 4.0f + 0.5f) + 2;
        int sb = (int)(v2 * 4.0f + 0.5f) + 2;
        int ci = (sr << 6) + (sg << 3) + sb;
        atomicAdd(&acc[ci],            inp[p * 3 + 0]);
        atomicAdd(&acc[512 + ci],      inp[p * 3 + 1]);
        atomicAdd(&acc[1024 + ci],     inp[p * 3 + 2]);
    }
    __syncthreads();

    long base = ((long)((iy + 2) * kSW + (ix + 2))) << 9;
    for (int i = threadIdx.x; i < 512; i += 256) {
        grid[base + i]            = acc[i];
        grid[kT3 + base + i]      = acc[512 + i];
        grid[2 * kT3 + base + i]  = acc[1024 + i];
    }
}

// Fused blur+slice: one 256-thread block per 16x16 pixel tile.
// Phase 1: stage the tile's 4 spatial cells of the SPLAT grid into LDS,
//          transposed Sv[cell][ch][b][r*8+g] (stencil reads stride-1).
// Phase 2: compute BOTH _convn iterations in-LDS (R6 blur2 algorithm; the
//          rare (r,g)-both-end lines read x-neighbor splat cells via
//          bounds-checked global loads, all L2-resident). Result in Sb.
// Phase 3: penta-linear slice gathers from Sb (color corner index is
//          transposed: (b<<6)+(r<<3)+g).
// gridB and the standalone blur launch are eliminated entirely.
__global__ __launch_bounds__(256) void blur_slice_kernel(const float* __restrict__ feat,
                                                         const float* __restrict__ hdrF,
                                                         const float* __restrict__ src,
                                                         float* __restrict__ out) {
    __shared__ float Sv[4 * 1536];   // [cell][ch][b][rg] of the splat
    __shared__ float Sb[4 * 1536];   // [cell][ch][b][rg] after both blur iters
    int tx = blockIdx.x, ty = blockIdx.y;   // 64 x 64 tiles

    const int* ip = (const int*)(hdrF + 8);
    int dr = ip[0], dg = ip[1], db = ip[2];
    int eHi = db - 1;

    // ---- Phase 1: stage 4 cells, transposed ----
    {
        const float4* g4 = (const float4*)src;
        for (int i = threadIdx.x; i < 1536; i += 256) {
            int cell = i / 384;
            int rem = i - cell * 384;
            int ch = rem >> 7, i4 = rem & 127;
            int cy = ty + 2 + (cell >> 1), cx = tx + 2 + (cell & 1);
            long cb4 = ((long)(cy * kSW + cx)) << 7;
            float4 q = g4[(long)ch * (kT3 / 4) + cb4 + i4];
            int rg = i4 >> 1;
            int b0 = (i4 & 1) * 4;
            float* S = Sv + cell * 1536 + ch * 512;
            S[(b0 + 0) * 64 + rg] = q.x;
            S[(b0 + 1) * 64 + rg] = q.y;
            S[(b0 + 2) * 64 + rg] = q.z;
            S[(b0 + 3) * 64 + rg] = q.w;
        }
    }
    __syncthreads();

    // ---- Phase 2: blur (768 line-tasks: cell x ch x 64 lines) ----
    #pragma unroll
    for (int k = 0; k < 3; ++k) {
        int task = threadIdx.x + (k << 8);
        int cell = task / 192;
        int t2 = task - cell * 192;
        int ch = t2 >> 6;
        int rg = t2 & 63;
        int r = rg >> 3, g = rg & 7;
        int cy = ty + 2 + (cell >> 1), cx = tx + 2 + (cell & 1);

        float* S = Sv + cell * 1536 + ch * 512;
        auto SV = [&](int b, int l) -> float { return S[b * 64 + l]; };
        auto gsp = [&](int ccy, int ccx, int rr, int gg, int bb) -> float {
            if (ccy < 2 || ccy > 66 || ccx < 2 || ccx > 66) return 0.0f;
            return src[(long)ch * kT3 + (((long)(ccy * kSW + ccx)) << 9) + (rr << 6) + (gg << 3) + bb];
        };

        bool gI = (g >= 1) && (g <= dg - 2);
        bool rI = (r >= 1) && (r <= dr - 2);

        float v[8];
        #pragma unroll
        for (int b = 0; b < 8; ++b) v[b] = SV(b, rg);

        auto o1_end = [&](int e) -> float {
            float Vm, Vp;
            if (gI)      { Vm = SV(e, rg - 1); Vp = SV(e, rg + 1); }
            else if (rI) { Vm = SV(e, rg - 8); Vp = SV(e, rg + 8); }
            else         { Vm = gsp(cy, cx - 1, r, g, e); Vp = gsp(cy, cx + 1, r, g, e); }
            return (Vm + Vp + 2.0f * SV(e, rg)) * 0.25f;
        };
        float o1_lo = o1_end(0);
        float o1_hi = o1_end(eHi);

        float o1[8];
        #pragma unroll
        for (int b = 0; b < 8; ++b) {
            float iv = 0.0f;
            if (b >= 1 && b <= 6) iv = ((v[b - 1] + v[b + 1]) + 2.0f * v[b]) * 0.25f;
            o1[b] = (b >= 1 && b <= db - 2) ? iv : (b == 0 ? o1_lo : (b == eHi ? o1_hi : 0.0f));
        }

        auto out1_in = [&](int r2, int g2, int e) -> float {
            int l2 = (r2 << 3) + g2;
            float C = SV(e, l2);
            float Nm, Np;
            if (g2 >= 1 && g2 <= dg - 2)      { Nm = SV(e, l2 - 1); Np = SV(e, l2 + 1); }
            else if (r2 >= 1 && r2 <= dr - 2) { Nm = SV(e, l2 - 8); Np = SV(e, l2 + 8); }
            else { Nm = gsp(cy, cx - 1, r2, g2, e); Np = gsp(cy, cx + 1, r2, g2, e); }
            return (Nm + Np + 2.0f * C) * 0.25f;
        };
        auto out1_x = [&](int cx2, int e) -> float {
            float C = gsp(cy, cx2, r, g, e);
            float Nm, Np;
            if (cx2 >= 1 && cx2 <= kSW - 2) { Nm = gsp(cy, cx2 - 1, r, g, e); Np = gsp(cy, cx2 + 1, r, g, e); }
            else                            { Nm = gsp(cy - 1, cx2, r, g, e); Np = gsp(cy + 1, cx2, r, g, e); }
            return (Nm + Np + 2.0f * C) * 0.25f;
        };
        auto o2_end = [&](int e, float o1e) -> float {
            float Xm, Xp;
            if (gI)      { Xm = out1_in(r, g - 1, e); Xp = out1_in(r, g + 1, e); }
            else if (rI) { Xm = out1_in(r - 1, g, e); Xp = out1_in(r + 1, g, e); }
            else         { Xm = out1_x(cx - 1, e);    Xp = out1_x(cx + 1, e); }
            return (Xm + Xp + 2.0f * o1e) * 0.25f;
        };
        float o2_lo = o2_end(0, o1_lo);
        float o2_hi = o2_end(eHi, o1_hi);

        float* B = Sb + cell * 1536 + ch * 512;
        #pragma unroll
        for (int b = 0; b < 8; ++b) {
            float iv = 0.0f;
            if (b >= 1 && b <= 6) iv = ((o1[b - 1] + o1[b + 1]) + 2.0f * o1[b]) * 0.25f;
            float o2 = (b >= 1 && b <= db - 2) ? iv : (b == 0 ? o2_lo : (b == eHi ? o2_hi : 0.0f));
            B[b * 64 + rg] = o2;
        }
    }
    __syncthreads();

    // ---- Phase 3: slice ----
    int lx = threadIdx.x & 15, ly = threadIdx.x >> 4;
    int y = (ty << 4) + ly, x = (tx << 4) + lx;
    int p = (y << 10) + x;

    float ya = (float)ly * 0.0625f;   // exact fractional part of y/16
    float xa = (float)lx * 0.0625f;

    int li[3], ri[3];
    float al[3];
    int d3[3] = {dr, dg, db};
    #pragma unroll
    for (int c = 0; c < 3; ++c) {
        float v0 = feat[p * 3 + c] - hdrF[c];
        float sv = v0 * 4.0f + 2.0f;
        int l = (int)sv;
        int dm = d3[c] - 1;
        l = l < 0 ? 0 : (l > dm ? dm : l);
        int rr = l + 1 > dm ? dm : l + 1;
        li[c] = l; ri[c] = rr; al[c] = sv - (float)l;
    }

    float spw[4];
    {
        float wy[2] = {1.0f - ya, ya};
        float wx[2] = {1.0f - xa, xa};
        spw[0] = wy[0] * wx[0]; spw[1] = wy[0] * wx[1];
        spw[2] = wy[1] * wx[0]; spw[3] = wy[1] * wx[1];
    }
    // color corners in TRANSPOSED layout: idx = (b<<6)+(r<<3)+g
    int cpi[8]; float cpw[8];
    {
        int rs[2] = {li[0], ri[0]}; float wrr[2] = {1.0f - al[0], al[0]};
        int gs[2] = {li[1], ri[1]}; float wgg[2] = {1.0f - al[1], al[1]};
        int bs[2] = {li[2], ri[2]}; float wbb[2] = {1.0f - al[2], al[2]};
        #pragma unroll
        for (int cr = 0; cr < 2; ++cr)
        #pragma unroll
        for (int cg = 0; cg < 2; ++cg)
        #pragma unroll
        for (int cb = 0; cb < 2; ++cb) {
            int k = (cr * 2 + cg) * 2 + cb;
            cpi[k] = (bs[cb] << 6) + (rs[cr] << 3) + gs[cg];
            cpw[k] = (wrr[cr] * wgg[cg]) * wbb[cb];
        }
    }

    float acc0 = 0.0f, acc1 = 0.0f, acc2 = 0.0f;
    #pragma unroll
    for (int k = 0; k < 4; ++k) {
        const float* B = Sb + k * 1536;
        #pragma unroll
        for (int j = 0; j < 8; ++j) {
            int si = cpi[j];
            float w = spw[k] * cpw[j];
            acc0 += w * B[si];
            acc1 += w * B[512 + si];
            acc2 += w * B[1024 + si];
        }
    }
    out[p * 3 + 0] = acc0;
    out[p * 3 + 1] = acc1;
    out[p * 3 + 2] = acc2;
}

}  // namespace

extern "C" void kernel_launch(void* const* d_in, const int* in_sizes, int n_in,
                              void* d_out, int out_size, void* d_ws, size_t ws_size,
                              hipStream_t stream) {
    const float* feat = (const float*)d_in[0];
    const float* inp  = (const float*)d_in[1];
    float* out = (float*)d_out;

    float* hdrF  = (float*)d_ws;
    float* part  = (float*)((char*)d_ws + 1024);       // 256 x 6 floats
    float* gridA = (float*)((char*)d_ws + 8192);       // splat (only grid)

    minmax_kernel<<<256, 256, 0, stream>>>(feat, part);
    params_kernel<<<1, 256, 0, stream>>>(part, hdrF);

    splat_kernel<<<dim3(65, 65), 256, 0, stream>>>(feat, inp, hdrF, gridA);
    blur_slice_kernel<<<dim3(64, 64), 256, 0, stream>>>(feat, hdrF, gridA, out);
}

// Round 8
// 150.671 us; speedup vs baseline: 1.4063x; 1.4063x over previous
//
#include <hip/hip_runtime.h>

namespace {

constexpr int kH  = 1024;
constexpr int kW  = 1024;
constexpr int kHW = kH * kW;
constexpr int kSH = 68;           // int(1023/16)+1+2*2
constexpr int kSW = 68;
constexpr int kD  = 8;            // max depth; features uniform [0,1) -> depth <= 8
constexpr int kT3 = kSH * kSW * kD * kD * kD;   // splat grid cells per channel
constexpr int kNC = 65;           // interior cells per axis [2,66]
// gridB: channel-interleaved blurred grid, [65*65 cells][512 rgb][4 (ch0..2,pad)]

__global__ void minmax_kernel(const float* __restrict__ feat, float* __restrict__ part) {
    // feat = 262144 chunks of 3 float4 (12 floats = 4 pixels); channel pattern
    // per chunk is fixed: q0={0,1,2,0} q1={1,2,0,1} q2={2,0,1,2}
    const float4* f4 = (const float4*)feat;
    float mn[3] = {1e30f, 1e30f, 1e30f};
    float mx[3] = {-1e30f, -1e30f, -1e30f};
    int tid = blockIdx.x * blockDim.x + threadIdx.x;
    int stride = gridDim.x * blockDim.x;
    for (int c = tid; c < kHW / 4; c += stride) {
        float4 q0 = f4[c * 3], q1 = f4[c * 3 + 1], q2 = f4[c * 3 + 2];
        mn[0] = fminf(mn[0], fminf(fminf(q0.x, q0.w), fminf(q1.z, q2.y)));
        mx[0] = fmaxf(mx[0], fmaxf(fmaxf(q0.x, q0.w), fmaxf(q1.z, q2.y)));
        mn[1] = fminf(mn[1], fminf(fminf(q0.y, q1.x), fminf(q1.w, q2.z)));
        mx[1] = fmaxf(mx[1], fmaxf(fmaxf(q0.y, q1.x), fmaxf(q1.w, q2.z)));
        mn[2] = fminf(mn[2], fminf(fminf(q0.z, q1.y), fminf(q2.x, q2.w)));
        mx[2] = fmaxf(mx[2], fmaxf(fmaxf(q0.z, q1.y), fmaxf(q2.x, q2.w)));
    }
    #pragma unroll
    for (int off = 32; off > 0; off >>= 1) {
        #pragma unroll
        for (int c = 0; c < 3; ++c) {
            mn[c] = fminf(mn[c], __shfl_down(mn[c], off, 64));
            mx[c] = fmaxf(mx[c], __shfl_down(mx[c], off, 64));
        }
    }
    __shared__ float smn[4][3], smx[4][3];
    int wave = threadIdx.x >> 6;
    if ((threadIdx.x & 63) == 0) {
        #pragma unroll
        for (int c = 0; c < 3; ++c) { smn[wave][c] = mn[c]; smx[wave][c] = mx[c]; }
    }
    __syncthreads();
    if (threadIdx.x == 0) {
        #pragma unroll
        for (int c = 0; c < 3; ++c) {
            part[blockIdx.x * 6 + c]     = fminf(fminf(smn[0][c], smn[1][c]), fminf(smn[2][c], smn[3][c]));
            part[blockIdx.x * 6 + 3 + c] = fmaxf(fmaxf(smx[0][c], smx[1][c]), fmaxf(smx[2][c], smx[3][c]));
        }
    }
}

__global__ void params_kernel(const float* __restrict__ part, float* __restrict__ hdrF) {
    int t = threadIdx.x;   // 256 threads, one per partial
    float mn[3], mx[3];
    #pragma unroll
    for (int c = 0; c < 3; ++c) { mn[c] = part[t * 6 + c]; mx[c] = part[t * 6 + 3 + c]; }
    #pragma unroll
    for (int off = 32; off > 0; off >>= 1) {
        #pragma unroll
        for (int c = 0; c < 3; ++c) {
            mn[c] = fminf(mn[c], __shfl_down(mn[c], off, 64));
            mx[c] = fmaxf(mx[c], __shfl_down(mx[c], off, 64));
        }
    }
    __shared__ float smn[4][3], smx[4][3];
    int wave = t >> 6;
    if ((t & 63) == 0) {
        #pragma unroll
        for (int c = 0; c < 3; ++c) { smn[wave][c] = mn[c]; smx[wave][c] = mx[c]; }
    }
    __syncthreads();
    if (t == 0) {
        int* ip = (int*)(hdrF + 8);
        #pragma unroll
        for (int c = 0; c < 3; ++c) {
            float bmn = fminf(fminf(smn[0][c], smn[1][c]), fminf(smn[2][c], smn[3][c]));
            float bmx = fmaxf(fmaxf(smx[0][c], smx[1][c]), fmaxf(smx[2][c], smx[3][c]));
            float delta = bmx - bmn;                        // fp32 sub, like numpy
            int depth = (int)((double)delta / 0.25) + 1 + 4;
            if (depth > kD) depth = kD;
            if (depth < 1) depth = 1;
            hdrF[c] = bmn;
            ip[c] = depth;
        }
    }
}

// Privatized splat: one block per INTERIOR cell [2,66]^2. Band rows of feat/inp
// are staged into LDS with aligned float4 loads (row byte offsets provably
// 16B-aligned), then LDS histogram + coalesced stores. Zero global atomics.
__global__ __launch_bounds__(256) void splat_kernel(const float* __restrict__ feat,
                                                    const float* __restrict__ inp,
                                                    const float* __restrict__ hdrF,
                                                    float* __restrict__ grid) {
    int ix = blockIdx.x, iy = blockIdx.y;          // band index 0..64
    int y0 = (iy == 0) ? 0 : 16 * iy - 8;
    int x0 = (ix == 0) ? 0 : 16 * ix - 8;
    int h = (iy == 0 || iy == 64) ? 8 : 16;
    int w = (ix == 0 || ix == 64) ? 8 : 16;

    __shared__ float acc[3 * 512];
    __shared__ float fS[16 * 48], iS[16 * 48];
    for (int i = threadIdx.x; i < 3 * 512; i += 256) acc[i] = 0.0f;

    int rowVec = (w * 3) >> 2;                     // float4 per row: 12 or 6
    int nvec = h * rowVec;
    const float4* f4 = (const float4*)(feat + ((long)y0 * kW + x0) * 3);
    const float4* i4 = (const float4*)(inp  + ((long)y0 * kW + x0) * 3);
    for (int t = threadIdx.x; t < nvec; t += 256) {
        int row = t / rowVec, q = t - row * rowVec;
        ((float4*)fS)[row * rowVec + q] = f4[row * (kW * 3 / 4) + q];
        ((float4*)iS)[row * rowVec + q] = i4[row * (kW * 3 / 4) + q];
    }
    __syncthreads();

    int t = threadIdx.x;
    int n = w * h;
    if (t < n) {
        int lx = t & (w - 1);
        int ly = (w == 16) ? (t >> 4) : (t >> 3);
        int o = (ly * w + lx) * 3;
        float v0 = fS[o + 0] - hdrF[0];
        float v1 = fS[o + 1] - hdrF[1];
        float v2 = fS[o + 2] - hdrF[2];
        int sr = (int)(v0 * 4.0f + 0.5f) + 2;   // /0.25 == *4 exact
        int sg = (int)(v1 * 4.0f + 0.5f) + 2;
        int sb = (int)(v2 * 4.0f + 0.5f) + 2;
        int ci = (sr << 6) + (sg << 3) + sb;
        atomicAdd(&acc[ci],        iS[o + 0]);
        atomicAdd(&acc[512 + ci],  iS[o + 1]);
        atomicAdd(&acc[1024 + ci], iS[o + 2]);
    }
    __syncthreads();

    long base = ((long)((iy + 2) * kSW + (ix + 2))) << 9;
    for (int i = threadIdx.x; i < 512; i += 256) {
        grid[base + i]            = acc[i];
        grid[kT3 + base + i]      = acc[512 + i];
        grid[2 * kT3 + base + i]  = acc[1024 + i];
    }
}

// Both _convn outer-iterations, LDS-resident per spatial cell (R6 algorithm).
// LDS layout Sv[ch][b][rg] padded to b-row stride 72 -> stencil reads stride-1,
// interleave write-out 2-way (free) banked. Output goes to gridB in
// channel-interleaved layout [cell65][rgb][4] for the slice's b128 gathers.
__global__ __launch_bounds__(192) void blur2_kernel(float4* __restrict__ dstB,
                                                    const float* __restrict__ src,
                                                    const float* __restrict__ hdrF) {
    int cx = blockIdx.x + 2, cy = blockIdx.y + 2;   // [2,66]
    const int* ip = (const int*)(hdrF + 8);
    int dr = ip[0], dg = ip[1], db = ip[2];

    __shared__ float Sv[3 * 576];   // [ch][b(8) stride 72][rg(64)]
    long cbase = ((long)(cy * kSW + cx)) << 9;

    {
        const float4* g4 = (const float4*)src;
        for (int i = threadIdx.x; i < 384; i += 192) {
            int ch = i >> 7, i4 = i & 127;
            float4 q = g4[(long)ch * (kT3 / 4) + (cbase >> 2) + i4];
            int rg = i4 >> 1;
            int b0 = (i4 & 1) * 4;
            float* S = Sv + ch * 576;
            S[(b0 + 0) * 72 + rg] = q.x;
            S[(b0 + 1) * 72 + rg] = q.y;
            S[(b0 + 2) * 72 + rg] = q.z;
            S[(b0 + 3) * 72 + rg] = q.w;
        }
    }
    __syncthreads();

    int ch = threadIdx.x >> 6;
    int rg = threadIdx.x & 63;
    int r = rg >> 3, g = rg & 7;

    float* S = Sv + ch * 576;
    auto SV = [&](int b, int l) -> float { return S[b * 72 + l]; };
    auto gsp = [&](int ccy, int ccx, int rr, int gg, int bb) -> float {
        if (ccy < 2 || ccy > 66 || ccx < 2 || ccx > 66) return 0.0f;
        return src[(long)ch * kT3 + (((long)(ccy * kSW + ccx)) << 9) + (rr << 6) + (gg << 3) + bb];
    };

    bool gI = (g >= 1) && (g <= dg - 2);
    bool rI = (r >= 1) && (r <= dr - 2);

    float v[8];
    #pragma unroll
    for (int b = 0; b < 8; ++b) v[b] = SV(b, rg);

    int eHi = db - 1;

    auto o1_end = [&](int e) -> float {
        float Vm, Vp;
        if (gI)      { Vm = SV(e, rg - 1); Vp = SV(e, rg + 1); }
        else if (rI) { Vm = SV(e, rg - 8); Vp = SV(e, rg + 8); }
        else         { Vm = gsp(cy, cx - 1, r, g, e); Vp = gsp(cy, cx + 1, r, g, e); }
        return (Vm + Vp + 2.0f * SV(e, rg)) * 0.25f;
    };
    float o1_lo = o1_end(0);
    float o1_hi = o1_end(eHi);

    float o1[8];
    #pragma unroll
    for (int b = 0; b < 8; ++b) {
        float iv = 0.0f;
        if (b >= 1 && b <= 6) iv = ((v[b - 1] + v[b + 1]) + 2.0f * v[b]) * 0.25f;
        o1[b] = (b >= 1 && b <= db - 2) ? iv : (b == 0 ? o1_lo : (b == eHi ? o1_hi : 0.0f));
    }

    auto out1_in = [&](int r2, int g2, int e) -> float {
        int l2 = (r2 << 3) + g2;
        float C = SV(e, l2);
        float Nm, Np;
        if (g2 >= 1 && g2 <= dg - 2)      { Nm = SV(e, l2 - 1); Np = SV(e, l2 + 1); }
        else if (r2 >= 1 && r2 <= dr - 2) { Nm = SV(e, l2 - 8); Np = SV(e, l2 + 8); }
        else { Nm = gsp(cy, cx - 1, r2, g2, e); Np = gsp(cy, cx + 1, r2, g2, e); }
        return (Nm + Np + 2.0f * C) * 0.25f;
    };
    auto out1_x = [&](int cx2, int e) -> float {
        float C = gsp(cy, cx2, r, g, e);
        float Nm, Np;
        if (cx2 >= 1 && cx2 <= kSW - 2) { Nm = gsp(cy, cx2 - 1, r, g, e); Np = gsp(cy, cx2 + 1, r, g, e); }
        else                            { Nm = gsp(cy - 1, cx2, r, g, e); Np = gsp(cy + 1, cx2, r, g, e); }
        return (Nm + Np + 2.0f * C) * 0.25f;
    };
    auto o2_end = [&](int e, float o1e) -> float {
        float Xm, Xp;
        if (gI)      { Xm = out1_in(r, g - 1, e); Xp = out1_in(r, g + 1, e); }
        else if (rI) { Xm = out1_in(r - 1, g, e); Xp = out1_in(r + 1, g, e); }
        else         { Xm = out1_x(cx - 1, e);    Xp = out1_x(cx + 1, e); }
        return (Xm + Xp + 2.0f * o1e) * 0.25f;
    };
    float o2_lo = o2_end(0, o1_lo);
    float o2_hi = o2_end(eHi, o1_hi);

    float o2[8];
    #pragma unroll
    for (int b = 0; b < 8; ++b) {
        float iv = 0.0f;
        if (b >= 1 && b <= 6) iv = ((o1[b - 1] + o1[b + 1]) + 2.0f * o1[b]) * 0.25f;
        o2[b] = (b >= 1 && b <= db - 2) ? iv : (b == 0 ? o2_lo : (b == eHi ? o2_hi : 0.0f));
    }

    __syncthreads();     // done reading Sv; reuse it for the blurred values
    #pragma unroll
    for (int b = 0; b < 8; ++b) S[b * 72 + rg] = o2[b];
    __syncthreads();

    // write channel-interleaved: gridB[cell][i=rgb][{ch0,ch1,ch2,0}]
    long cellBase = (long)(blockIdx.y * kNC + blockIdx.x) * 512;
    for (int i = threadIdx.x; i < 512; i += 192) {
        int b = i & 7, l = i >> 3;
        dstB[cellBase + i] = make_float4(Sv[b * 72 + l],
                                         Sv[576 + b * 72 + l],
                                         Sv[1152 + b * 72 + l],
                                         0.0f);
    }
}

// LDS-staged slice: one block per 16x16 pixel tile; stage 4 interleaved cells
// (32 KB + pad). Each (spatial, r, g) corner fetches its b-pair x 3 channels
// with two ds_read_b128 and lerps b arithmetically (a_eff=0 when ri==li).
__global__ __launch_bounds__(256) void slice_kernel(const float* __restrict__ feat,
                                                    const float* __restrict__ hdrF,
                                                    const float4* __restrict__ gridB,
                                                    float* __restrict__ out) {
    __shared__ float4 Sc[4 * 512 + 1];   // [cell(2x2)][rgb][ch4], +1 pad for b=7 pair
    int tx = blockIdx.x, ty = blockIdx.y;   // 64 x 64 tiles

    for (int i = threadIdx.x; i < 2048; i += 256) {
        int cell = i >> 9, i4 = i & 511;
        int cy = ty + (cell >> 1), cx = tx + (cell & 1);      // gridB cell coords
        Sc[i] = gridB[(long)(cy * kNC + cx) * 512 + i4];
    }
    if (threadIdx.x == 0) Sc[2048] = make_float4(0.f, 0.f, 0.f, 0.f);
    __syncthreads();

    const int* ip = (const int*)(hdrF + 8);
    int d3[3] = {ip[0], ip[1], ip[2]};
    int lx = threadIdx.x & 15, ly = threadIdx.x >> 4;
    int y = (ty << 4) + ly, x = (tx << 4) + lx;
    int p = (y << 10) + x;

    float ya = (float)ly * 0.0625f;   // exact fractional part of y/16
    float xa = (float)lx * 0.0625f;

    int li[3], ri[3];
    float al[3];
    #pragma unroll
    for (int c = 0; c < 3; ++c) {
        float v0 = feat[p * 3 + c] - hdrF[c];
        float sv = v0 * 4.0f + 2.0f;
        int l = (int)sv;
        int dm = d3[c] - 1;
        l = l < 0 ? 0 : (l > dm ? dm : l);
        int rr = l + 1 > dm ? dm : l + 1;
        li[c] = l; ri[c] = rr; al[c] = sv - (float)l;
    }

    float spw[4];
    {
        float wy[2] = {1.0f - ya, ya};
        float wx[2] = {1.0f - xa, xa};
        spw[0] = wy[0] * wx[0]; spw[1] = wy[0] * wx[1];
        spw[2] = wy[1] * wx[0]; spw[3] = wy[1] * wx[1];
    }
    int rs[2] = {li[0], ri[0]}; float wrr[2] = {1.0f - al[0], al[0]};
    int gs[2] = {li[1], ri[1]}; float wgg[2] = {1.0f - al[1], al[1]};
    int bq = li[2];
    float aeff = (ri[2] > li[2]) ? al[2] : 0.0f;

    float acc0 = 0.0f, acc1 = 0.0f, acc2 = 0.0f;
    #pragma unroll
    for (int k = 0; k < 4; ++k) {
        const float4* C = Sc + (k << 9);
        #pragma unroll
        for (int cr = 0; cr < 2; ++cr)
        #pragma unroll
        for (int cg = 0; cg < 2; ++cg) {
            int idx = ((rs[cr] << 3) + gs[cg]) * 8 + bq;
            float4 q0 = C[idx];
            float4 q1 = C[idx + 1];
            float w = spw[k] * wrr[cr] * wgg[cg];
            acc0 += w * (q0.x + aeff * (q1.x - q0.x));
            acc1 += w * (q0.y + aeff * (q1.y - q0.y));
            acc2 += w * (q0.z + aeff * (q1.z - q0.z));
        }
    }
    out[p * 3 + 0] = acc0;
    out[p * 3 + 1] = acc1;
    out[p * 3 + 2] = acc2;
}

}  // namespace

extern "C" void kernel_launch(void* const* d_in, const int* in_sizes, int n_in,
                              void* d_out, int out_size, void* d_ws, size_t ws_size,
                              hipStream_t stream) {
    const float* feat = (const float*)d_in[0];
    const float* inp  = (const float*)d_in[1];
    float* out = (float*)d_out;

    float*  hdrF  = (float*)d_ws;
    float*  part  = (float*)((char*)d_ws + 1024);       // 256 x 6 floats
    float*  gridA = (float*)((char*)d_ws + 8192);       // splat, standard layout
    float4* gridB = (float4*)((char*)d_ws + 8192 + 3 * (size_t)kT3 * sizeof(float));

    minmax_kernel<<<256, 256, 0, stream>>>(feat, part);
    params_kernel<<<1, 256, 0, stream>>>(part, hdrF);

    splat_kernel<<<dim3(65, 65), 256, 0, stream>>>(feat, inp, hdrF, gridA);
    blur2_kernel<<<dim3(65, 65), 192, 0, stream>>>(gridB, gridA, hdrF);
    slice_kernel<<<dim3(64, 64), 256, 0, stream>>>(feat, hdrF, gridB, out);
}

// Round 9
// 142.225 us; speedup vs baseline: 1.4898x; 1.0594x over previous
//
#include <hip/hip_runtime.h>

namespace {

constexpr int kH  = 1024;
constexpr int kW  = 1024;
constexpr int kHW = kH * kW;
constexpr int kSH = 68;           // int(1023/16)+1+2*2
constexpr int kSW = 68;
constexpr int kD  = 8;            // max depth; features uniform [0,1) -> depth <= 8
constexpr int kT3 = kSH * kSW * kD * kD * kD;   // grid cells per channel
// gridA (splat): per-cell TRANSPOSED layout idxT = (b<<6)+(r<<3)+g
// gridB (blur):  per-cell STANDARD  layout idx  = (r<<6)+(g<<3)+b

__global__ void minmax_kernel(const float* __restrict__ feat, float* __restrict__ part) {
    // feat = 262144 chunks of 3 float4 (12 floats = 4 pixels); channel pattern
    // per chunk is fixed: q0={0,1,2,0} q1={1,2,0,1} q2={2,0,1,2}
    const float4* f4 = (const float4*)feat;
    float mn[3] = {1e30f, 1e30f, 1e30f};
    float mx[3] = {-1e30f, -1e30f, -1e30f};
    int tid = blockIdx.x * blockDim.x + threadIdx.x;
    int stride = gridDim.x * blockDim.x;
    for (int c = tid; c < kHW / 4; c += stride) {
        float4 q0 = f4[c * 3], q1 = f4[c * 3 + 1], q2 = f4[c * 3 + 2];
        mn[0] = fminf(mn[0], fminf(fminf(q0.x, q0.w), fminf(q1.z, q2.y)));
        mx[0] = fmaxf(mx[0], fmaxf(fmaxf(q0.x, q0.w), fmaxf(q1.z, q2.y)));
        mn[1] = fminf(mn[1], fminf(fminf(q0.y, q1.x), fminf(q1.w, q2.z)));
        mx[1] = fmaxf(mx[1], fmaxf(fmaxf(q0.y, q1.x), fmaxf(q1.w, q2.z)));
        mn[2] = fminf(mn[2], fminf(fminf(q0.z, q1.y), fminf(q2.x, q2.w)));
        mx[2] = fmaxf(mx[2], fmaxf(fmaxf(q0.z, q1.y), fmaxf(q2.x, q2.w)));
    }
    #pragma unroll
    for (int off = 32; off > 0; off >>= 1) {
        #pragma unroll
        for (int c = 0; c < 3; ++c) {
            mn[c] = fminf(mn[c], __shfl_down(mn[c], off, 64));
            mx[c] = fmaxf(mx[c], __shfl_down(mx[c], off, 64));
        }
    }
    __shared__ float smn[4][3], smx[4][3];
    int wave = threadIdx.x >> 6;
    if ((threadIdx.x & 63) == 0) {
        #pragma unroll
        for (int c = 0; c < 3; ++c) { smn[wave][c] = mn[c]; smx[wave][c] = mx[c]; }
    }
    __syncthreads();
    if (threadIdx.x == 0) {
        #pragma unroll
        for (int c = 0; c < 3; ++c) {
            part[blockIdx.x * 6 + c]     = fminf(fminf(smn[0][c], smn[1][c]), fminf(smn[2][c], smn[3][c]));
            part[blockIdx.x * 6 + 3 + c] = fmaxf(fmaxf(smx[0][c], smx[1][c]), fmaxf(smx[2][c], smx[3][c]));
        }
    }
}

__global__ void params_kernel(const float* __restrict__ part, float* __restrict__ hdrF) {
    int t = threadIdx.x;   // 256 threads, one per partial
    float mn[3], mx[3];
    #pragma unroll
    for (int c = 0; c < 3; ++c) { mn[c] = part[t * 6 + c]; mx[c] = part[t * 6 + 3 + c]; }
    #pragma unroll
    for (int off = 32; off > 0; off >>= 1) {
        #pragma unroll
        for (int c = 0; c < 3; ++c) {
            mn[c] = fminf(mn[c], __shfl_down(mn[c], off, 64));
            mx[c] = fmaxf(mx[c], __shfl_down(mx[c], off, 64));
        }
    }
    __shared__ float smn[4][3], smx[4][3];
    int wave = t >> 6;
    if ((t & 63) == 0) {
        #pragma unroll
        for (int c = 0; c < 3; ++c) { smn[wave][c] = mn[c]; smx[wave][c] = mx[c]; }
    }
    __syncthreads();
    if (t == 0) {
        int* ip = (int*)(hdrF + 8);
        #pragma unroll
        for (int c = 0; c < 3; ++c) {
            float bmn = fminf(fminf(smn[0][c], smn[1][c]), fminf(smn[2][c], smn[3][c]));
            float bmx = fmaxf(fmaxf(smx[0][c], smx[1][c]), fmaxf(smx[2][c], smx[3][c]));
            float delta = bmx - bmn;                        // fp32 sub, like numpy
            int depth = (int)((double)delta / 0.25) + 1 + 4;
            if (depth > kD) depth = kD;
            if (depth < 1) depth = 1;
            hdrF[c] = bmn;
            ip[c] = depth;
        }
    }
}

// Privatized splat: one block per INTERIOR cell [2,66]^2; LDS histogram in
// standard (r<<6|g<<3|b) order, written out in TRANSPOSED order (b<<6|r<<3|g)
// so blur2's staging is a straight vector copy. Zero global atomics.
__global__ __launch_bounds__(256) void splat_kernel(const float* __restrict__ feat,
                                                    const float* __restrict__ inp,
                                                    const float* __restrict__ hdrF,
                                                    float* __restrict__ grid) {
    int ix = blockIdx.x, iy = blockIdx.y;          // band index 0..64
    int y0 = (iy == 0) ? 0 : 16 * iy - 8;
    int x0 = (ix == 0) ? 0 : 16 * ix - 8;
    int h = (iy == 0 || iy == 64) ? 8 : 16;
    int w = (ix == 0 || ix == 64) ? 8 : 16;

    __shared__ float acc[3 * 512];
    __shared__ float fS[16 * 48], iS[16 * 48];
    for (int i = threadIdx.x; i < 3 * 512; i += 256) acc[i] = 0.0f;

    int rowVec = (w * 3) >> 2;                     // float4 per row: 12 or 6
    int nvec = h * rowVec;
    const float4* f4 = (const float4*)(feat + ((long)y0 * kW + x0) * 3);
    const float4* i4 = (const float4*)(inp  + ((long)y0 * kW + x0) * 3);
    for (int t = threadIdx.x; t < nvec; t += 256) {
        int row = t / rowVec, q = t - row * rowVec;
        ((float4*)fS)[row * rowVec + q] = f4[row * (kW * 3 / 4) + q];
        ((float4*)iS)[row * rowVec + q] = i4[row * (kW * 3 / 4) + q];
    }
    __syncthreads();

    int t = threadIdx.x;
    int n = w * h;
    if (t < n) {
        int lx = t & (w - 1);
        int ly = (w == 16) ? (t >> 4) : (t >> 3);
        int o = (ly * w + lx) * 3;
        float v0 = fS[o + 0] - hdrF[0];
        float v1 = fS[o + 1] - hdrF[1];
        float v2 = fS[o + 2] - hdrF[2];
        int sr = (int)(v0 * 4.0f + 0.5f) + 2;   // /0.25 == *4 exact
        int sg = (int)(v1 * 4.0f + 0.5f) + 2;
        int sb = (int)(v2 * 4.0f + 0.5f) + 2;
        int ci = (sr << 6) + (sg << 3) + sb;
        atomicAdd(&acc[ci],        iS[o + 0]);
        atomicAdd(&acc[512 + ci],  iS[o + 1]);
        atomicAdd(&acc[1024 + ci], iS[o + 2]);
    }
    __syncthreads();

    long base = ((long)((iy + 2) * kSW + (ix + 2))) << 9;
    for (int i = threadIdx.x; i < 512; i += 256) {
        // output position i in transposed layout (b<<6|r<<3|g)
        int b = i >> 6, r = (i >> 3) & 7, g = i & 7;
        int s = (r << 6) + (g << 3) + b;
        grid[base + i]            = acc[s];
        grid[kT3 + base + i]      = acc[512 + s];
        grid[2 * kT3 + base + i]  = acc[1024 + s];
    }
}

// Both _convn outer-iterations, LDS-resident per spatial cell (R6 algorithm).
// gridA is transposed -> staging is a straight float4 copy into the padded
// stencil layout Sv[ch][b (stride 72)][r*8+g]. Output written straight from
// registers to gridB in STANDARD layout (each thread's 8 b-values contiguous).
__global__ __launch_bounds__(192) void blur2_kernel(float* __restrict__ dst,
                                                    const float* __restrict__ src,
                                                    const float* __restrict__ hdrF) {
    int cx = blockIdx.x + 2, cy = blockIdx.y + 2;   // [2,66]
    const int* ip = (const int*)(hdrF + 8);
    int dr = ip[0], dg = ip[1], db = ip[2];

    __shared__ float Sv[3 * 576];   // [ch][b(8) stride 72][rg(64)]
    long cbase = ((long)(cy * kSW + cx)) << 9;

    {
        const float4* g4 = (const float4*)src;
        for (int i = threadIdx.x; i < 384; i += 192) {
            int ch = i >> 7, i4 = i & 127;
            float4 q = g4[(long)ch * (kT3 / 4) + (cbase >> 2) + i4];
            int b = i4 >> 4;
            int rg = ((i4 >> 1) & 7) * 8 + (i4 & 1) * 4;
            *(float4*)&Sv[ch * 576 + b * 72 + rg] = q;
        }
    }
    __syncthreads();

    int ch = threadIdx.x >> 6;
    int rg = threadIdx.x & 63;
    int r = rg >> 3, g = rg & 7;

    float* S = Sv + ch * 576;
    auto SV = [&](int b, int l) -> float { return S[b * 72 + l]; };
    auto gsp = [&](int ccy, int ccx, int rr, int gg, int bb) -> float {
        if (ccy < 2 || ccy > 66 || ccx < 2 || ccx > 66) return 0.0f;
        return src[(long)ch * kT3 + (((long)(ccy * kSW + ccx)) << 9) + (bb << 6) + (rr << 3) + gg];
    };

    bool gI = (g >= 1) && (g <= dg - 2);
    bool rI = (r >= 1) && (r <= dr - 2);

    float v[8];
    #pragma unroll
    for (int b = 0; b < 8; ++b) v[b] = SV(b, rg);

    int eHi = db - 1;

    auto o1_end = [&](int e) -> float {
        float Vm, Vp;
        if (gI)      { Vm = SV(e, rg - 1); Vp = SV(e, rg + 1); }
        else if (rI) { Vm = SV(e, rg - 8); Vp = SV(e, rg + 8); }
        else         { Vm = gsp(cy, cx - 1, r, g, e); Vp = gsp(cy, cx + 1, r, g, e); }
        return (Vm + Vp + 2.0f * SV(e, rg)) * 0.25f;
    };
    float o1_lo = o1_end(0);
    float o1_hi = o1_end(eHi);

    float o1[8];
    #pragma unroll
    for (int b = 0; b < 8; ++b) {
        float iv = 0.0f;
        if (b >= 1 && b <= 6) iv = ((v[b - 1] + v[b + 1]) + 2.0f * v[b]) * 0.25f;
        o1[b] = (b >= 1 && b <= db - 2) ? iv : (b == 0 ? o1_lo : (b == eHi ? o1_hi : 0.0f));
    }

    auto out1_in = [&](int r2, int g2, int e) -> float {
        int l2 = (r2 << 3) + g2;
        float C = SV(e, l2);
        float Nm, Np;
        if (g2 >= 1 && g2 <= dg - 2)      { Nm = SV(e, l2 - 1); Np = SV(e, l2 + 1); }
        else if (r2 >= 1 && r2 <= dr - 2) { Nm = SV(e, l2 - 8); Np = SV(e, l2 + 8); }
        else { Nm = gsp(cy, cx - 1, r2, g2, e); Np = gsp(cy, cx + 1, r2, g2, e); }
        return (Nm + Np + 2.0f * C) * 0.25f;
    };
    auto out1_x = [&](int cx2, int e) -> float {
        float C = gsp(cy, cx2, r, g, e);
        float Nm, Np;
        if (cx2 >= 1 && cx2 <= kSW - 2) { Nm = gsp(cy, cx2 - 1, r, g, e); Np = gsp(cy, cx2 + 1, r, g, e); }
        else                            { Nm = gsp(cy - 1, cx2, r, g, e); Np = gsp(cy + 1, cx2, r, g, e); }
        return (Nm + Np + 2.0f * C) * 0.25f;
    };
    auto o2_end = [&](int e, float o1e) -> float {
        float Xm, Xp;
        if (gI)      { Xm = out1_in(r, g - 1, e); Xp = out1_in(r, g + 1, e); }
        else if (rI) { Xm = out1_in(r - 1, g, e); Xp = out1_in(r + 1, g, e); }
        else         { Xm = out1_x(cx - 1, e);    Xp = out1_x(cx + 1, e); }
        return (Xm + Xp + 2.0f * o1e) * 0.25f;
    };
    float o2_lo = o2_end(0, o1_lo);
    float o2_hi = o2_end(eHi, o1_hi);

    float o2[8];
    #pragma unroll
    for (int b = 0; b < 8; ++b) {
        float iv = 0.0f;
        if (b >= 1 && b <= 6) iv = ((o1[b - 1] + o1[b + 1]) + 2.0f * o1[b]) * 0.25f;
        o2[b] = (b >= 1 && b <= db - 2) ? iv : (b == 0 ? o2_lo : (b == eHi ? o2_hi : 0.0f));
    }

    // standard layout: this thread's 8 b-values are contiguous at rg*8
    float* dp = dst + (long)ch * kT3 + cbase + (rg << 3);
    *(float4*)dp       = make_float4(o2[0], o2[1], o2[2], o2[3]);
    *(float4*)(dp + 4) = make_float4(o2[4], o2[5], o2[6], o2[7]);
}

// LDS-staged slice (R6 structure): one block per 16x16 pixel tile, stage 4
// cells x 512 x 3ch (24 KB). Gather uses ADJACENT b-pairs (si, si+1) merged
// into ds_read2_b32 by the compiler, with arithmetic b-lerp (aeff=0 when
// clamped) -> 48 paired reads instead of 96 independent ones.
__global__ __launch_bounds__(256) void slice_kernel(const float* __restrict__ feat,
                                                    const float* __restrict__ hdrF,
                                                    const float* __restrict__ grid,
                                                    float* __restrict__ out) {
    __shared__ float sg[3 * 4 * 512 + 8];   // [ch][cell][512], pad for b=7 pair
    int tx = blockIdx.x, ty = blockIdx.y;   // 64 x 64 tiles

    {
        const float4* g4 = (const float4*)grid;
        float4* s4 = (float4*)sg;
        #pragma unroll
        for (int it = 0; it < 2; ++it) {
            int i = threadIdx.x + it * 256;       // float4 index within a channel plane [0,512)
            int cell = i >> 7;                    // 0..3 = (dy<<1)|dx
            int ci4 = i & 127;
            int cy = ty + 2 + (cell >> 1), cx = tx + 2 + (cell & 1);
            long cbase4 = ((long)(cy * kSW + cx)) << 7;   // 128 float4 per cell
            #pragma unroll
            for (int ch = 0; ch < 3; ++ch)
                s4[ch * 512 + i] = g4[(long)ch * (kT3 / 4) + cbase4 + ci4];
        }
    }
    __syncthreads();

    const int* ip = (const int*)(hdrF + 8);
    int d3[3] = {ip[0], ip[1], ip[2]};
    int lx = threadIdx.x & 15, ly = threadIdx.x >> 4;
    int y = (ty << 4) + ly, x = (tx << 4) + lx;
    int p = (y << 10) + x;

    float ya = (float)ly * 0.0625f;   // exact fractional part of y/16
    float xa = (float)lx * 0.0625f;

    int li[3], ri[3];
    float al[3];
    #pragma unroll
    for (int c = 0; c < 3; ++c) {
        float v0 = feat[p * 3 + c] - hdrF[c];
        float sv = v0 * 4.0f + 2.0f;
        int l = (int)sv;
        int dm = d3[c] - 1;
        l = l < 0 ? 0 : (l > dm ? dm : l);
        int rr = l + 1 > dm ? dm : l + 1;
        li[c] = l; ri[c] = rr; al[c] = sv - (float)l;
    }

    float spw[4];
    {
        float wy[2] = {1.0f - ya, ya};
        float wx[2] = {1.0f - xa, xa};
        spw[0] = wy[0] * wx[0]; spw[1] = wy[0] * wx[1];
        spw[2] = wy[1] * wx[0]; spw[3] = wy[1] * wx[1];
    }
    int rs[2] = {li[0], ri[0]}; float wrr[2] = {1.0f - al[0], al[0]};
    int gs[2] = {li[1], ri[1]}; float wgg[2] = {1.0f - al[1], al[1]};
    int bq = li[2];
    float aeff = (ri[2] > li[2]) ? al[2] : 0.0f;

    float acc0 = 0.0f, acc1 = 0.0f, acc2 = 0.0f;
    #pragma unroll
    for (int k = 0; k < 4; ++k) {
        #pragma unroll
        for (int cr = 0; cr < 2; ++cr)
        #pragma unroll
        for (int cg = 0; cg < 2; ++cg) {
            int si = (k << 9) + (rs[cr] << 6) + (gs[cg] << 3) + bq;
            float w = spw[k] * wrr[cr] * wgg[cg];
            float a0 = sg[si],        a1 = sg[si + 1];
            float b0 = sg[2048 + si], b1 = sg[2048 + si + 1];
            float c0 = sg[4096 + si], c1 = sg[4096 + si + 1];
            acc0 += w * (a0 + aeff * (a1 - a0));
            acc1 += w * (b0 + aeff * (b1 - b0));
            acc2 += w * (c0 + aeff * (c1 - c0));
        }
    }
    out[p * 3 + 0] = acc0;
    out[p * 3 + 1] = acc1;
    out[p * 3 + 2] = acc2;
}

}  // namespace

extern "C" void kernel_launch(void* const* d_in, const int* in_sizes, int n_in,
                              void* d_out, int out_size, void* d_ws, size_t ws_size,
                              hipStream_t stream) {
    const float* feat = (const float*)d_in[0];
    const float* inp  = (const float*)d_in[1];
    float* out = (float*)d_out;

    float* hdrF  = (float*)d_ws;
    float* part  = (float*)((char*)d_ws + 1024);       // 256 x 6 floats
    float* gridA = (float*)((char*)d_ws + 8192);       // splat, transposed cells
    float* gridB = gridA + 3 * (size_t)kT3;            // blurred, standard cells

    minmax_kernel<<<256, 256, 0, stream>>>(feat, part);
    params_kernel<<<1, 256, 0, stream>>>(part, hdrF);

    splat_kernel<<<dim3(65, 65), 256, 0, stream>>>(feat, inp, hdrF, gridA);
    blur2_kernel<<<dim3(65, 65), 192, 0, stream>>>(gridB, gridA, hdrF);
    slice_kernel<<<dim3(64, 64), 256, 0, stream>>>(feat, hdrF, gridB, out);
}